// Round 1
// baseline (9333.581 us; speedup 1.0000x reference)
//
#include <hip/hip_runtime.h>
#include <hip/hip_bf16.h>

#define B_ 128
#define S_ 256
#define I_ 512
#define H_ 1024
#define P_ 128   // column groups for the recurrent kernel (8 h-cols each)

typedef float  f32x4  __attribute__((ext_vector_type(4)));
typedef __bf16 bf16x8 __attribute__((ext_vector_type(8)));
typedef unsigned short u16x8 __attribute__((ext_vector_type(8)));

__device__ __forceinline__ unsigned short f2bf(float f) {
    unsigned u = __float_as_uint(f);
    unsigned r = (u + 0x7fffu + ((u >> 16) & 1u)) >> 16;   // RNE
    return (unsigned short)r;
}
__device__ __forceinline__ float bf2f(unsigned short s) {
    return __uint_as_float(((unsigned)s) << 16);
}

// ---------------------------------------------------------------------------
// Pack W_ih [3H, I] into MFMA B-fragment order, bf16 single.
// Layout: [p 128][nt 2][ks 16][lane 64][j 8]
// packed col c (=lane&15): nt0: c<8 -> r-row 8p+c ; c>=8 -> z-row H+8p+(c-8)
//                          nt1: c<8 -> n-row 2H+8p+c ; c>=8 -> zero pad
// ---------------------------------------------------------------------------
__global__ __launch_bounds__(256) void pack_wih(const float* __restrict__ W,
                                                unsigned short* __restrict__ out) {
    int gid = blockIdx.x * 256 + threadIdx.x;        // 262144 total
    int lane = gid & 63, ks = (gid >> 6) & 15, nt = (gid >> 10) & 1, p = gid >> 11;
    int c = lane & 15, quad = lane >> 4;
    int k = ks * 32 + quad * 8;
    int n = 0; bool valid = true;
    if (nt == 0) n = (c < 8) ? (p * 8 + c) : (H_ + p * 8 + (c - 8));
    else { if (c < 8) n = 2 * H_ + p * 8 + c; else valid = false; }
    const float* src = W + n * I_ + k;
    u16x8 v;
#pragma unroll
    for (int j = 0; j < 8; j++) v[j] = valid ? f2bf(src[j]) : (unsigned short)0;
    *(u16x8*)(out + (size_t)gid * 8) = v;
}

// ---------------------------------------------------------------------------
// Pack W_hh [3H, H] into B-fragment order, bf16 split hi/lo.
// Layout: [p 128][nt 2][ks 32][lane 64][j 8]  (same column mapping as pack_wih)
// ---------------------------------------------------------------------------
__global__ __launch_bounds__(256) void pack_whh(const float* __restrict__ W,
                                                unsigned short* __restrict__ hi,
                                                unsigned short* __restrict__ lo) {
    int gid = blockIdx.x * 256 + threadIdx.x;        // 524288 total
    int lane = gid & 63, ks = (gid >> 6) & 31, nt = (gid >> 11) & 1, p = gid >> 12;
    int c = lane & 15, quad = lane >> 4;
    int k = ks * 32 + quad * 8;
    int n = 0; bool valid = true;
    if (nt == 0) n = (c < 8) ? (p * 8 + c) : (H_ + p * 8 + (c - 8));
    else { if (c < 8) n = 2 * H_ + p * 8 + c; else valid = false; }
    const float* src = W + n * H_ + k;
    u16x8 vh, vl;
#pragma unroll
    for (int j = 0; j < 8; j++) {
        float f = valid ? src[j] : 0.f;
        unsigned short h = f2bf(f);
        unsigned short l = f2bf(f - bf2f(h));
        vh[j] = valid ? h : (unsigned short)0;
        vl[j] = valid ? l : (unsigned short)0;
    }
    *(u16x8*)(hi + (size_t)gid * 8) = vh;
    *(u16x8*)(lo + (size_t)gid * 8) = vl;
}

// ---------------------------------------------------------------------------
// Phase A: G[t] = x_t @ W_ih.T (bf16 MFMA, single product)  +  fused sx.
// Grid: 8192 = 256 t * 32 pc. Block 256 thr (4 waves), per wave 2 M-tiles.
// Each block: 128 rows x 128 packed cols (pc -> 4 p-groups -> 8 N-tiles).
// G layout: [t][p][b 128][24]: pos 0..7 = r, 8..15 = z, 16..23 = n.
// sx[t*128+b] computed (fp32, exact) by pc==0 blocks.
// ---------------------------------------------------------------------------
__global__ __launch_bounds__(256) void phase_a(const float* __restrict__ x,
                                               const float* __restrict__ Watt,
                                               const unsigned short* __restrict__ WihP,
                                               unsigned short* __restrict__ G,
                                               float* __restrict__ sx) {
    int bid = blockIdx.x;
    int t = bid >> 5, pc = bid & 31;
    int tid = threadIdx.x, w = tid >> 6, lane = tid & 63;
    int quad = lane >> 4, c = lane & 15;

    f32x4 acc[2][8];
#pragma unroll
    for (int mi = 0; mi < 2; mi++)
#pragma unroll
        for (int n8 = 0; n8 < 8; n8++) acc[mi][n8] = (f32x4){0.f, 0.f, 0.f, 0.f};
    float shp[2] = {0.f, 0.f};

    for (int ks = 0; ks < 16; ks++) {
        int k = ks * 32 + quad * 8;
        bf16x8 af[2];
        float xf[2][8];
#pragma unroll
        for (int mi = 0; mi < 2; mi++) {
            int b = (w * 2 + mi) * 16 + c;
            const float4* xp4 = (const float4*)(x + ((size_t)b * S_ + t) * I_ + k);
            float4 a0 = xp4[0], a1 = xp4[1];
            xf[mi][0] = a0.x; xf[mi][1] = a0.y; xf[mi][2] = a0.z; xf[mi][3] = a0.w;
            xf[mi][4] = a1.x; xf[mi][5] = a1.y; xf[mi][6] = a1.z; xf[mi][7] = a1.w;
            bf16x8 av;
#pragma unroll
            for (int j = 0; j < 8; j++) av[j] = (__bf16)xf[mi][j];
            af[mi] = av;
        }
        if (pc == 0) {
            const float4* wp4 = (const float4*)(Watt + k);
            float4 w0 = wp4[0], w1 = wp4[1];
            float wv[8] = {w0.x, w0.y, w0.z, w0.w, w1.x, w1.y, w1.z, w1.w};
#pragma unroll
            for (int mi = 0; mi < 2; mi++)
#pragma unroll
                for (int j = 0; j < 8; j++) shp[mi] += xf[mi][j] * wv[j];
        }
        bf16x8 bf[8];
#pragma unroll
        for (int n8 = 0; n8 < 8; n8++) {
            int p = pc * 4 + (n8 >> 1), nt = n8 & 1;
            bf[n8] = *(const bf16x8*)(WihP + ((((size_t)p * 2 + nt) * 16 + ks) * 64 + lane) * 8);
        }
#pragma unroll
        for (int mi = 0; mi < 2; mi++)
#pragma unroll
            for (int n8 = 0; n8 < 8; n8++)
                acc[mi][n8] = __builtin_amdgcn_mfma_f32_16x16x32_bf16(af[mi], bf[n8], acc[mi][n8], 0, 0, 0);
    }

    // store D tiles -> G   (C layout: col = lane&15, row = quad*4 + reg)
#pragma unroll
    for (int mi = 0; mi < 2; mi++) {
        int m = w * 2 + mi;
#pragma unroll
        for (int n8 = 0; n8 < 8; n8++) {
            int p = pc * 4 + (n8 >> 1), nt = n8 & 1;
            if (nt == 1 && c >= 8) continue;             // pad cols
            int pos = (nt == 0) ? c : (16 + c);
#pragma unroll
            for (int r = 0; r < 4; r++) {
                int row = m * 16 + quad * 4 + r;
                G[((size_t)(t * 128 + p) * 128 + row) * 24 + pos] = f2bf(acc[mi][n8][r]);
            }
        }
    }

    if (pc == 0) {
#pragma unroll
        for (int mi = 0; mi < 2; mi++) {
            float v = shp[mi];
            v += __shfl_xor(v, 16, 64);
            v += __shfl_xor(v, 32, 64);
            if (lane < 16) sx[t * 128 + (w * 2 + mi) * 16 + lane] = v;
        }
    }
}

// ---------------------------------------------------------------------------
// One recurrence step. Grid: 128 blocks (block p owns h-cols 8p..8p+7),
// 512 threads = 8 waves, wave w owns M-tile w (batch rows 16w..16w+15).
// gh = h @ W_hh.T with 3-product bf16 split; sh = h_hi . Wa_h co-issued VALU;
// softmax over batch redundant per block; gates lane-local in C layout.
// ---------------------------------------------------------------------------
__global__ __launch_bounds__(512) void gru_step(int t,
        const unsigned short* __restrict__ Hhi_r, const unsigned short* __restrict__ Hlo_r,
        unsigned short* __restrict__ Hhi_w, unsigned short* __restrict__ Hlo_w,
        const unsigned short* __restrict__ WhhHi, const unsigned short* __restrict__ WhhLo,
        const unsigned short* __restrict__ G, const float* __restrict__ sx,
        const float* __restrict__ Watt, const float* __restrict__ batt,
        const float* __restrict__ bih, const float* __restrict__ bhh,
        float* __restrict__ out) {
    int p = blockIdx.x;
    int tid = threadIdx.x, w = tid >> 6, lane = tid & 63;
    int quad = lane >> 4, c = lane & 15;

    __shared__ float sh_lds[128];
    __shared__ float score_lds[128];
    __shared__ unsigned short g_lds[128 * 24];

    // stage this block's G[t] slice (6 KB) into LDS while the K-loop runs
    {
        const unsigned int* gsrc = (const unsigned int*)(G + (size_t)(t * 128 + p) * 128 * 24);
        unsigned int* gdst = (unsigned int*)g_lds;
        for (int i = tid; i < 1536; i += 512) gdst[i] = gsrc[i];
    }

    f32x4 acc0 = (f32x4){0.f, 0.f, 0.f, 0.f};
    f32x4 acc1 = (f32x4){0.f, 0.f, 0.f, 0.f};
    float shp = 0.f;
    int b0 = w * 16 + c;                       // A-fragment row (batch index)

#pragma unroll 2
    for (int ks = 0; ks < 32; ks++) {
        int k = ks * 32 + quad * 8;
        bf16x8 ah = *(const bf16x8*)(Hhi_r + (size_t)b0 * H_ + k);
        bf16x8 al = *(const bf16x8*)(Hlo_r + (size_t)b0 * H_ + k);
        const float4* wp4 = (const float4*)(Watt + I_ + k);
        float4 w0 = wp4[0], w1 = wp4[1];
        shp += (float)ah[0] * w0.x + (float)ah[1] * w0.y + (float)ah[2] * w0.z + (float)ah[3] * w0.w
             + (float)ah[4] * w1.x + (float)ah[5] * w1.y + (float)ah[6] * w1.z + (float)ah[7] * w1.w;
        size_t boff = (((size_t)p * 2 + 0) * 32 + ks) * 512 + (size_t)lane * 8;
        bf16x8 bh0 = *(const bf16x8*)(WhhHi + boff);
        bf16x8 bl0 = *(const bf16x8*)(WhhLo + boff);
        bf16x8 bh1 = *(const bf16x8*)(WhhHi + boff + 16384);
        bf16x8 bl1 = *(const bf16x8*)(WhhLo + boff + 16384);
        acc0 = __builtin_amdgcn_mfma_f32_16x16x32_bf16(ah, bh0, acc0, 0, 0, 0);
        acc0 = __builtin_amdgcn_mfma_f32_16x16x32_bf16(al, bh0, acc0, 0, 0, 0);
        acc0 = __builtin_amdgcn_mfma_f32_16x16x32_bf16(ah, bl0, acc0, 0, 0, 0);
        acc1 = __builtin_amdgcn_mfma_f32_16x16x32_bf16(ah, bh1, acc1, 0, 0, 0);
        acc1 = __builtin_amdgcn_mfma_f32_16x16x32_bf16(al, bh1, acc1, 0, 0, 0);
        acc1 = __builtin_amdgcn_mfma_f32_16x16x32_bf16(ah, bl1, acc1, 0, 0, 0);
    }

    // reduce sh partials over quads (lanes 16 apart hold same row, different k)
    shp += __shfl_xor(shp, 16, 64);
    shp += __shfl_xor(shp, 32, 64);
    if (lane < 16) sh_lds[w * 16 + lane] = shp;
    __syncthreads();
    if (tid < 128) score_lds[tid] = sh_lds[tid] + sx[t * 128 + tid] + batt[0];
    __syncthreads();

    // wave-parallel softmax stats (each wave redundantly)
    float s0 = score_lds[lane], s1 = score_lds[lane + 64];
    float mx = fmaxf(s0, s1);
#pragma unroll
    for (int off = 1; off < 64; off <<= 1) mx = fmaxf(mx, __shfl_xor(mx, off, 64));
    float pe = __expf(s0 - mx) + __expf(s1 - mx);
#pragma unroll
    for (int off = 1; off < 64; off <<= 1) pe += __shfl_xor(pe, off, 64);
    float rden = 1.f / pe;

    // gates: C layout row = quad*4+r, col = lane&15. Lanes c<8 own h-col j.
    int cl = c & 7;
    int j = p * 8 + cl;
    float bihr = bih[j], bihz = bih[H_ + j], bihn = bih[2 * H_ + j];
    float bhhr = bhh[j], bhhz = bhh[H_ + j], bhhn = bhh[2 * H_ + j];
#pragma unroll
    for (int r = 0; r < 4; r++) {
        int b = w * 16 + quad * 4 + r;
        float att = __expf(score_lds[b] - mx) * rden;
        float ghr_raw = acc0[r];
        float ghz = __shfl_xor(ghr_raw, 8, 64);     // z lives in lane c+8
        float ghn = acc1[r];
        float Gr = bf2f(g_lds[b * 24 + cl]);
        float Gz = bf2f(g_lds[b * 24 + 8 + cl]);
        float Gn = bf2f(g_lds[b * 24 + 16 + cl]);
        float ir = att * Gr + bihr;
        float iz = att * Gz + bihz;
        float in_ = att * Gn + bihn;
        float hr = ghr_raw + bhhr;
        float hz = ghz + bhhz;
        float hn_g = ghn + bhhn;
        float rg = 1.f / (1.f + __expf(-(ir + hr)));
        float zg = 1.f / (1.f + __expf(-(iz + hz)));
        float ng = tanhf(in_ + rg * hn_g);
        float hp = bf2f(Hhi_r[(size_t)b * H_ + j]) + bf2f(Hlo_r[(size_t)b * H_ + j]);
        float hnew = (1.f - zg) * ng + zg * hp;
        if (c < 8) {
            out[((size_t)b * S_ + t) * H_ + j] = hnew;
            unsigned short hi = f2bf(hnew);
            unsigned short lo = f2bf(hnew - bf2f(hi));
            Hhi_w[(size_t)b * H_ + j] = hi;
            Hlo_w[(size_t)b * H_ + j] = lo;
            if (t == S_ - 1) out[(size_t)B_ * S_ * H_ + (size_t)b * H_ + j] = hnew;
        }
    }
}

// ---------------------------------------------------------------------------
extern "C" void kernel_launch(void* const* d_in, const int* in_sizes, int n_in,
                              void* d_out, int out_size, void* d_ws, size_t ws_size,
                              hipStream_t stream) {
    (void)in_sizes; (void)n_in; (void)out_size; (void)ws_size;
    const float* x    = (const float*)d_in[0];
    const float* Watt = (const float*)d_in[1];
    const float* batt = (const float*)d_in[2];
    const float* Wih  = (const float*)d_in[3];
    const float* Whh  = (const float*)d_in[4];
    const float* bih  = (const float*)d_in[5];
    const float* bhh  = (const float*)d_in[6];
    float* out = (float*)d_out;

    char* ws = (char*)d_ws;
    size_t off = 0;
    unsigned short* G     = (unsigned short*)(ws + off); off += 201326592ULL; // 256*128*128*24 * 2B
    unsigned short* WihP  = (unsigned short*)(ws + off); off += 4194304ULL;
    unsigned short* WhhHi = (unsigned short*)(ws + off); off += 8388608ULL;
    unsigned short* WhhLo = (unsigned short*)(ws + off); off += 8388608ULL;
    float*          sx    = (float*)(ws + off);          off += 131072ULL;
    unsigned short* H0hi  = (unsigned short*)(ws + off); off += 262144ULL;
    unsigned short* H0lo  = (unsigned short*)(ws + off); off += 262144ULL;
    unsigned short* H1hi  = (unsigned short*)(ws + off); off += 262144ULL;
    unsigned short* H1lo  = (unsigned short*)(ws + off); off += 262144ULL;

    hipMemsetAsync(H0hi, 0, 524288, stream);   // zero H0hi + H0lo (adjacent)
    pack_wih<<<1024, 256, 0, stream>>>(Wih, WihP);
    pack_whh<<<2048, 256, 0, stream>>>(Whh, WhhHi, WhhLo);
    phase_a<<<8192, 256, 0, stream>>>(x, Watt, WihP, G, sx);
    for (int t = 0; t < S_; t++) {
        const unsigned short* hr_hi = (t & 1) ? H1hi : H0hi;
        const unsigned short* hr_lo = (t & 1) ? H1lo : H0lo;
        unsigned short* hw_hi = (t & 1) ? H0hi : H1hi;
        unsigned short* hw_lo = (t & 1) ? H0lo : H1lo;
        gru_step<<<P_, 512, 0, stream>>>(t, hr_hi, hr_lo, hw_hi, hw_lo,
                                         WhhHi, WhhLo, G, sx, Watt, batt, bih, bhh, out);
    }
}

// Round 2
// 5866.085 us; speedup vs baseline: 1.5911x; 1.5911x over previous
//
#include <hip/hip_runtime.h>
#include <hip/hip_bf16.h>

#define B_ 128
#define S_ 256
#define I_ 512
#define H_ 1024

typedef float  f32x4  __attribute__((ext_vector_type(4)));
typedef __bf16 bf16x8 __attribute__((ext_vector_type(8)));
typedef unsigned short u16x8 __attribute__((ext_vector_type(8)));

__device__ __forceinline__ unsigned short f2bf(float f) {
    unsigned u = __float_as_uint(f);
    unsigned r = (u + 0x7fffu + ((u >> 16) & 1u)) >> 16;   // RNE
    return (unsigned short)r;
}
__device__ __forceinline__ float bf2f(unsigned short s) {
    return __uint_as_float(((unsigned)s) << 16);
}

// ---------------------------------------------------------------------------
// Pack W_ih [3H, I] into MFMA B-fragment order, bf16 single (unchanged, R1-verified).
// Layout: [p 128][nt 2][ks 16][lane 64][j 8]
// ---------------------------------------------------------------------------
__global__ __launch_bounds__(256) void pack_wih(const float* __restrict__ W,
                                                unsigned short* __restrict__ out) {
    int gid = blockIdx.x * 256 + threadIdx.x;        // 262144 total
    int lane = gid & 63, ks = (gid >> 6) & 15, nt = (gid >> 10) & 1, p = gid >> 11;
    int c = lane & 15, quad = lane >> 4;
    int k = ks * 32 + quad * 8;
    int n = 0; bool valid = true;
    if (nt == 0) n = (c < 8) ? (p * 8 + c) : (H_ + p * 8 + (c - 8));
    else { if (c < 8) n = 2 * H_ + p * 8 + c; else valid = false; }
    const float* src = W + (size_t)n * I_ + k;
    u16x8 v;
#pragma unroll
    for (int j = 0; j < 8; j++) v[j] = valid ? f2bf(src[j]) : (unsigned short)0;
    *(u16x8*)(out + (size_t)gid * 8) = v;
}

// ---------------------------------------------------------------------------
// Pack W_hh [3H, H] bf16 hi/lo split into three arrays:
//   Bhi0 [p][ks 32][lane 64][8]      (nt0 hi fragments, full)        4 MB
//   Bhi1c[p][ks 32][32][8]           (nt1 hi, compact c<8 lanes)     2 MB
//   Blo  [p][nt 2][ks 32][lane 64][8](lo fragments, padded w/ zeros) 8 MB
// Same row/k mapping as R1 (verified).
// ---------------------------------------------------------------------------
__global__ __launch_bounds__(256) void pack_whh(const float* __restrict__ W,
                                                unsigned short* __restrict__ Bhi0,
                                                unsigned short* __restrict__ Bhi1c,
                                                unsigned short* __restrict__ Blo) {
    int gid = blockIdx.x * 256 + threadIdx.x;        // 524288 total
    int lane = gid & 63, ks = (gid >> 6) & 31, nt = (gid >> 11) & 1, p = gid >> 12;
    int c = lane & 15, quad = lane >> 4;
    int k = ks * 32 + quad * 8;
    int n = 0; bool valid = true;
    if (nt == 0) n = (c < 8) ? (p * 8 + c) : (H_ + p * 8 + (c - 8));
    else { if (c < 8) n = 2 * H_ + p * 8 + c; else valid = false; }
    const float* src = W + (size_t)n * H_ + k;
    u16x8 vh, vl;
#pragma unroll
    for (int j = 0; j < 8; j++) {
        float f = valid ? src[j] : 0.f;
        unsigned short h = f2bf(f);
        unsigned short l = f2bf(f - bf2f(h));
        vh[j] = valid ? h : (unsigned short)0;
        vl[j] = valid ? l : (unsigned short)0;
    }
    *(u16x8*)(Blo + ((((size_t)p * 2 + nt) * 32 + ks) * 64 + lane) * 8) = vl;
    if (nt == 0)
        *(u16x8*)(Bhi0 + (((size_t)p * 32 + ks) * 64 + lane) * 8) = vh;
    else if (c < 8)
        *(u16x8*)(Bhi1c + (((size_t)p * 32 + ks) * 32 + quad * 8 + c) * 8) = vh;
}

// ---------------------------------------------------------------------------
// Pack x into MFMA A-fragment bf16 layout via LDS transpose (coalesced both ways).
// Gx layout: [t 256][m 8][ks 16][lane 64][8]
// ---------------------------------------------------------------------------
__global__ __launch_bounds__(256) void pack_x(const float* __restrict__ x,
                                              unsigned short* __restrict__ Gx) {
    int bid = blockIdx.x;                 // 2048 = 256 t * 8 m
    int t = bid >> 3, m = bid & 7;
    int tid = threadIdx.x;
    __shared__ unsigned short tile[16 * 520];     // +8 u16 row pad vs 512
#pragma unroll
    for (int pass = 0; pass < 8; pass++) {
        int idx = pass * 256 + tid;               // 0..2047
        int row = idx >> 7, c4 = idx & 127;
        float4 v = *(const float4*)(x + ((size_t)(m * 16 + row) * S_ + t) * I_ + c4 * 4);
        unsigned short* d = &tile[row * 520 + c4 * 4];
        d[0] = f2bf(v.x); d[1] = f2bf(v.y); d[2] = f2bf(v.z); d[3] = f2bf(v.w);
    }
    __syncthreads();
#pragma unroll
    for (int pass = 0; pass < 4; pass++) {
        int chunk = pass * 256 + tid;             // 0..1023
        int ks = chunk >> 6, lane = chunk & 63;
        int c = lane & 15, kq = lane >> 4;
        int k = ks * 32 + kq * 8;
        u16x8 v = *(const u16x8*)(&tile[c * 520 + k]);
        *(u16x8*)(Gx + (((size_t)(t * 8 + m) * 16 + ks) * 64 + lane) * 8) = v;
    }
}

// ---------------------------------------------------------------------------
// sx[t*128+b] = x[b][t][:] . Wa_x  (fp32 exact, coalesced row reads)
// ---------------------------------------------------------------------------
__global__ __launch_bounds__(256) void sx_kernel(const float* __restrict__ x,
                                                 const float* __restrict__ Watt,
                                                 float* __restrict__ sx) {
    int t = blockIdx.x;
    int w = threadIdx.x >> 6, lane = threadIdx.x & 63;
    float4 wa0 = *(const float4*)(Watt + lane * 8);
    float4 wa1 = *(const float4*)(Watt + lane * 8 + 4);
    for (int i = 0; i < 32; i++) {
        int b = w * 32 + i;
        const float4* xp = (const float4*)(x + ((size_t)b * S_ + t) * I_ + lane * 8);
        float4 a0 = xp[0], a1 = xp[1];
        float s = a0.x * wa0.x + a0.y * wa0.y + a0.z * wa0.z + a0.w * wa0.w
                + a1.x * wa1.x + a1.y * wa1.y + a1.z * wa1.z + a1.w * wa1.w;
#pragma unroll
        for (int off = 1; off < 64; off <<= 1) s += __shfl_xor(s, off, 64);
        if (lane == 0) sx[t * 128 + b] = s;
    }
}

// ---------------------------------------------------------------------------
// Phase A: G[t] = x_t @ W_ih.T (bf16 MFMA). A-frags from Gx (coalesced).
// G stored in C-fragment layout, per (t,p,m): 384 u16:
//   [0..255]   = nt0: lane*4 + r          (r/z gates)
//   [256..383] = nt1 compact: (quad*8+c')*4 + r   (n gate, c'<8)
// ---------------------------------------------------------------------------
__global__ __launch_bounds__(256) void phase_a(const unsigned short* __restrict__ Gx,
                                               const unsigned short* __restrict__ WihP,
                                               unsigned short* __restrict__ Gfrag) {
    int bid = blockIdx.x;                 // 8192 = 256 t * 32 pc
    int t = bid >> 5, pc = bid & 31;
    int tid = threadIdx.x, w = tid >> 6, lane = tid & 63;
    int quad = lane >> 4, c = lane & 15;

    f32x4 acc[2][8];
#pragma unroll
    for (int mi = 0; mi < 2; mi++)
#pragma unroll
        for (int n8 = 0; n8 < 8; n8++) acc[mi][n8] = (f32x4){0.f, 0.f, 0.f, 0.f};

    for (int ks = 0; ks < 16; ks++) {
        bf16x8 af[2];
#pragma unroll
        for (int mi = 0; mi < 2; mi++)
            af[mi] = *(const bf16x8*)(Gx + (((size_t)(t * 8 + w * 2 + mi) * 16 + ks) * 64 + lane) * 8);
        bf16x8 bf[8];
#pragma unroll
        for (int n8 = 0; n8 < 8; n8++) {
            int p = pc * 4 + (n8 >> 1), nt = n8 & 1;
            bf[n8] = *(const bf16x8*)(WihP + ((((size_t)p * 2 + nt) * 16 + ks) * 64 + lane) * 8);
        }
#pragma unroll
        for (int mi = 0; mi < 2; mi++)
#pragma unroll
            for (int n8 = 0; n8 < 8; n8++)
                acc[mi][n8] = __builtin_amdgcn_mfma_f32_16x16x32_bf16(af[mi], bf[n8], acc[mi][n8], 0, 0, 0);
    }

#pragma unroll
    for (int mi = 0; mi < 2; mi++) {
        int m = w * 2 + mi;
#pragma unroll
        for (int n8 = 0; n8 < 8; n8++) {
            int p = pc * 4 + (n8 >> 1), nt = n8 & 1;
            size_t base16 = ((size_t)(t * 128 + p) * 8 + m) * 384;
            unsigned v0 = (unsigned)f2bf(acc[mi][n8][0]) | ((unsigned)f2bf(acc[mi][n8][1]) << 16);
            unsigned v1 = (unsigned)f2bf(acc[mi][n8][2]) | ((unsigned)f2bf(acc[mi][n8][3]) << 16);
            uint2 vv; vv.x = v0; vv.y = v1;
            if (nt == 0) {
                *(uint2*)(Gfrag + base16 + (size_t)lane * 4) = vv;
            } else if (c < 8) {
                *(uint2*)(Gfrag + base16 + 256 + (size_t)(quad * 8 + c) * 4) = vv;
            }
        }
    }
}

// ---------------------------------------------------------------------------
// Persistent recurrence kernel. 128 blocks x 512 thr, 1 block/CU (<=256 CUs =>
// co-resident; required for the software grid barrier). Block p owns h-cols
// 8p..8p+7. W_hh-hi lives in LDS for all 256 steps (survives the per-step
// L2 invalidation that the agent-scope barrier acquire performs).
// h ping-pong buffers are stored in A-fragment layout [m 8][ks 32][lane 64][8]
// so all K-loop global loads are fully coalesced 16 B/lane.
// ---------------------------------------------------------------------------
__global__ __launch_bounds__(512) void gru_persist(
        const unsigned short* __restrict__ Gfrag,
        const float* __restrict__ sx,
        const unsigned short* __restrict__ Bhi0,
        const unsigned short* __restrict__ Bhi1c,
        const unsigned short* __restrict__ Blo,
        unsigned short* __restrict__ H0hi, unsigned short* __restrict__ H0lo,
        unsigned short* __restrict__ H1hi, unsigned short* __restrict__ H1lo,
        const float* __restrict__ Watt, const float* __restrict__ batt,
        const float* __restrict__ bih, const float* __restrict__ bhh,
        float* __restrict__ out, unsigned* __restrict__ bar) {
    int p = blockIdx.x;
    int tid = threadIdx.x, w = tid >> 6, lane = tid & 63;
    int quad = lane >> 4, c = lane & 15, cl = c & 7;

    __shared__ unsigned short bhi0[16384];   // 32 KB  [ks 32][lane 64][8]
    __shared__ unsigned short bhi1[8192];    // 16 KB  [ks 32][32][8]
    __shared__ unsigned short bzero[8];      // 16 B zero fragment
    __shared__ float wa_lds[1024];           // Wa h-part
    __shared__ float sh_lds[128];
    __shared__ float score_lds[128];

    {   // stage W_hh hi slices into LDS (once, persists across all steps)
        const uint4* s0 = (const uint4*)(Bhi0 + (size_t)p * 16384);
        uint4* d0 = (uint4*)bhi0;
        for (int i = tid; i < 2048; i += 512) d0[i] = s0[i];
        const uint4* s1 = (const uint4*)(Bhi1c + (size_t)p * 8192);
        uint4* d1 = (uint4*)bhi1;
        for (int i = tid; i < 1024; i += 512) d1[i] = s1[i];
        if (tid < 8) bzero[tid] = 0;
        for (int i = tid; i < 1024; i += 512) wa_lds[i] = Watt[I_ + i];
    }
    float ba = batt[0];
    int j = p * 8 + cl;
    float bihr = bih[j], bihz = bih[H_ + j], bihn = bih[2 * H_ + j];
    float bhhr = bhh[j], bhhz = bhh[H_ + j], bhhn = bhh[2 * H_ + j];
    __syncthreads();

    unsigned short* curHi = H0hi; unsigned short* curLo = H0lo;
    unsigned short* nxtHi = H1hi; unsigned short* nxtLo = H1lo;
    const unsigned short* blo0 = Blo + (size_t)p * 32768;   // [nt][ks][lane][8]
    const unsigned short* blo1 = blo0 + 16384;
    int nt1o = (quad * 8 + c) * 8;                          // valid for c<8

    for (int t = 0; t < S_; t++) {
        // ---- prologue loads (issued early, consumed in epilogue) ----
        uint2 gr, gz, gn; gr.x = gr.y = gz.x = gz.y = gn.x = gn.y = 0u;
        float hp[4] = {0.f, 0.f, 0.f, 0.f};
        if (c < 8) {
            size_t b16 = ((size_t)(t * 128 + p) * 8 + w) * 384;
            gr = *(const uint2*)(Gfrag + b16 + (size_t)(quad * 16 + cl) * 4);
            gz = *(const uint2*)(Gfrag + b16 + (size_t)(quad * 16 + 8 + cl) * 4);
            gn = *(const uint2*)(Gfrag + b16 + 256 + (size_t)(quad * 8 + cl) * 4);
#pragma unroll
            for (int r = 0; r < 4; r++) {
                size_t ha = (((size_t)w * 32 + (p >> 2)) * 64 + (quad * 4 + r) + 16 * (p & 3)) * 8 + cl;
                hp[r] = bf2f(curHi[ha]) + bf2f(curLo[ha]);
            }
        }
        float sxv = 0.f;
        if (tid < 128) sxv = sx[t * 128 + tid];

        // ---- K-loop: gh = h @ Whh.T (3-product bf16 split) + sh dot ----
        f32x4 acc0 = (f32x4){0.f, 0.f, 0.f, 0.f};
        f32x4 acc1 = (f32x4){0.f, 0.f, 0.f, 0.f};
        float shp = 0.f;
#pragma unroll 2
        for (int ks = 0; ks < 32; ks++) {
            size_t aoff = (((size_t)w * 32 + ks) * 64 + lane) * 8;
            bf16x8 ah = *(const bf16x8*)(curHi + aoff);
            bf16x8 al = *(const bf16x8*)(curLo + aoff);
            bf16x8 bh0 = *(const bf16x8*)(bhi0 + ((size_t)ks * 64 + lane) * 8);
            const unsigned short* bp1 = (c < 8) ? (bhi1 + (size_t)ks * 256 + nt1o) : bzero;
            bf16x8 bh1 = *(const bf16x8*)bp1;
            size_t loff = ((size_t)ks * 64 + lane) * 8;
            bf16x8 bl0 = *(const bf16x8*)(blo0 + loff);
            bf16x8 bl1 = *(const bf16x8*)(blo1 + loff);
            int k = ks * 32 + quad * 8;
            float4 w0 = *(const float4*)(wa_lds + k);
            float4 w1 = *(const float4*)(wa_lds + k + 4);
            shp += (float)ah[0] * w0.x + (float)ah[1] * w0.y + (float)ah[2] * w0.z + (float)ah[3] * w0.w
                 + (float)ah[4] * w1.x + (float)ah[5] * w1.y + (float)ah[6] * w1.z + (float)ah[7] * w1.w;
            acc0 = __builtin_amdgcn_mfma_f32_16x16x32_bf16(ah, bh0, acc0, 0, 0, 0);
            acc0 = __builtin_amdgcn_mfma_f32_16x16x32_bf16(al, bh0, acc0, 0, 0, 0);
            acc0 = __builtin_amdgcn_mfma_f32_16x16x32_bf16(ah, bl0, acc0, 0, 0, 0);
            acc1 = __builtin_amdgcn_mfma_f32_16x16x32_bf16(ah, bh1, acc1, 0, 0, 0);
            acc1 = __builtin_amdgcn_mfma_f32_16x16x32_bf16(al, bh1, acc1, 0, 0, 0);
            acc1 = __builtin_amdgcn_mfma_f32_16x16x32_bf16(ah, bl1, acc1, 0, 0, 0);
        }

        // ---- sh reduce + score ----
        shp += __shfl_xor(shp, 16, 64);
        shp += __shfl_xor(shp, 32, 64);
        if (lane < 16) sh_lds[w * 16 + lane] = shp;
        __syncthreads();
        if (tid < 128) score_lds[tid] = sh_lds[tid] + sxv + ba;
        __syncthreads();

        // ---- softmax stats (each wave redundantly) ----
        float s0 = score_lds[lane], s1 = score_lds[lane + 64];
        float mx = fmaxf(s0, s1);
#pragma unroll
        for (int off = 1; off < 64; off <<= 1) mx = fmaxf(mx, __shfl_xor(mx, off, 64));
        float pe = __expf(s0 - mx) + __expf(s1 - mx);
#pragma unroll
        for (int off = 1; off < 64; off <<= 1) pe += __shfl_xor(pe, off, 64);
        float rden = 1.f / pe;

        // ---- gates + h update (C layout: row=quad*4+r, col=lane&15) ----
#pragma unroll
        for (int r = 0; r < 4; r++) {
            int b = w * 16 + quad * 4 + r;
            float att = __expf(score_lds[b] - mx) * rden;
            float ghr_raw = acc0[r];
            float ghz = __shfl_xor(ghr_raw, 8, 64);     // z lives in lane c+8
            float ghn = acc1[r];
            unsigned grw = (r < 2) ? gr.x : gr.y;
            unsigned gzw = (r < 2) ? gz.x : gz.y;
            unsigned gnw = (r < 2) ? gn.x : gn.y;
            int sh16 = (r & 1) * 16;
            float Gr = bf2f((unsigned short)(grw >> sh16));
            float Gz = bf2f((unsigned short)(gzw >> sh16));
            float Gn = bf2f((unsigned short)(gnw >> sh16));
            float ir = att * Gr + bihr;
            float iz = att * Gz + bihz;
            float in_ = att * Gn + bihn;
            float hr = ghr_raw + bhhr;
            float hz = ghz + bhhz;
            float hn_g = ghn + bhhn;
            float rg = 1.f / (1.f + __expf(-(ir + hr)));
            float zg = 1.f / (1.f + __expf(-(iz + hz)));
            float ng = tanhf(in_ + rg * hn_g);
            float hnew = (1.f - zg) * ng + zg * hp[r];
            if (c < 8) {
                out[((size_t)b * S_ + t) * H_ + j] = hnew;
                unsigned short hi16 = f2bf(hnew);
                unsigned short lo16 = f2bf(hnew - bf2f(hi16));
                size_t ha = (((size_t)w * 32 + (p >> 2)) * 64 + (quad * 4 + r) + 16 * (p & 3)) * 8 + cl;
                nxtHi[ha] = hi16; nxtLo[ha] = lo16;
                if (t == S_ - 1) out[(size_t)B_ * S_ * H_ + (size_t)b * H_ + j] = hnew;
            }
        }

        // ---- software grid barrier (agent scope; monotonic targets) ----
        __syncthreads();                     // drains vmcnt => stores in L2
        if (tid == 0) {
            __hip_atomic_fetch_add(bar + (p & 3) * 32, 1u,
                                   __ATOMIC_RELEASE, __HIP_MEMORY_SCOPE_AGENT);
            unsigned tgt = (unsigned)(t + 1) * 32u;   // 128 blocks / 4 counters
            for (int i = 0; i < 4; i++) {
                while (__hip_atomic_load(bar + i * 32,
                                         __ATOMIC_ACQUIRE, __HIP_MEMORY_SCOPE_AGENT) < tgt)
                    __builtin_amdgcn_s_sleep(2);
            }
            __builtin_amdgcn_fence(__ATOMIC_ACQUIRE, "agent");
        }
        __syncthreads();

        unsigned short* th = curHi; curHi = nxtHi; nxtHi = th;
        unsigned short* tl = curLo; curLo = nxtLo; nxtLo = tl;
    }
}

// ---------------------------------------------------------------------------
extern "C" void kernel_launch(void* const* d_in, const int* in_sizes, int n_in,
                              void* d_out, int out_size, void* d_ws, size_t ws_size,
                              hipStream_t stream) {
    (void)in_sizes; (void)n_in; (void)out_size; (void)ws_size;
    const float* x    = (const float*)d_in[0];
    const float* Watt = (const float*)d_in[1];
    const float* batt = (const float*)d_in[2];
    const float* Wih  = (const float*)d_in[3];
    const float* Whh  = (const float*)d_in[4];
    const float* bih  = (const float*)d_in[5];
    const float* bhh  = (const float*)d_in[6];
    float* out = (float*)d_out;

    char* ws = (char*)d_ws;
    size_t off = 0;
    unsigned short* Gfrag = (unsigned short*)(ws + off); off += 201326592ULL; // 256*128*8*384*2
    unsigned short* Gx    = (unsigned short*)(ws + off); off += 33554432ULL;  // 256*8*16*64*8*2
    unsigned short* WihP  = (unsigned short*)(ws + off); off += 4194304ULL;
    unsigned short* Bhi0  = (unsigned short*)(ws + off); off += 4194304ULL;
    unsigned short* Bhi1c = (unsigned short*)(ws + off); off += 2097152ULL;
    unsigned short* Blo   = (unsigned short*)(ws + off); off += 8388608ULL;
    float*          sx    = (float*)(ws + off);          off += 131072ULL;
    unsigned short* H0hi  = (unsigned short*)(ws + off); off += 262144ULL;
    unsigned short* H0lo  = (unsigned short*)(ws + off); off += 262144ULL;
    unsigned short* H1hi  = (unsigned short*)(ws + off); off += 262144ULL;
    unsigned short* H1lo  = (unsigned short*)(ws + off); off += 262144ULL;
    unsigned*       bar   = (unsigned*)(ws + off);       off += 512ULL;

    hipMemsetAsync(H0hi, 0, 524288, stream);   // zero H0hi + H0lo (adjacent)
    hipMemsetAsync(bar, 0, 512, stream);       // barrier counters
    pack_wih<<<1024, 256, 0, stream>>>(Wih, WihP);
    pack_whh<<<2048, 256, 0, stream>>>(Whh, Bhi0, Bhi1c, Blo);
    pack_x<<<2048, 256, 0, stream>>>(x, Gx);
    sx_kernel<<<256, 256, 0, stream>>>(x, Watt, sx);
    phase_a<<<8192, 256, 0, stream>>>(Gx, WihP, Gfrag);
    gru_persist<<<128, 512, 0, stream>>>(Gfrag, sx, Bhi0, Bhi1c, Blo,
                                         H0hi, H0lo, H1hi, H1lo,
                                         Watt, batt, bih, bhh, out, bar);
}